// Round 1
// baseline (286.525 us; speedup 1.0000x reference)
//
#include <hip/hip_runtime.h>
#include <hip/hip_bf16.h>

// Problem: N=1024 rows (online/mom emb, D=256), queue [256][65536], temp scalar.
// loss = mean_n( logsumexp([pos_n, (online@queue)_n]/t) - pos_n/t )  (fwd: alpha mix is identity)

#define NROWS 1024
#define DDIM  256
#define KQ    65536

#define BM 256
#define BN 128
#define BK 64
#define KP 72            // padded LDS k-stride (bf16 elems): 144B rows -> 2-way max bank aliasing (free)
#define NPART 1024       // per-row partial count: 512 n-blocks * 2 wave-col-bands

typedef short short8 __attribute__((ext_vector_type(8)));
typedef float floatx4 __attribute__((ext_vector_type(4)));

__device__ __forceinline__ unsigned short f2bf(float f) {
    unsigned int u = __float_as_uint(f);
    u += 0x7FFFu + ((u >> 16) & 1u);   // round-to-nearest-even
    return (unsigned short)(u >> 16);
}

__global__ __launch_bounds__(256, 2)
void gemm_softmax_kernel(const float* __restrict__ A,      // online [1024][256]
                         const float* __restrict__ Q,      // queue  [256][65536]
                         const float* __restrict__ temp,
                         float2* __restrict__ partials)    // [1024][NPART]
{
    __shared__ unsigned short Al[BM][KP];   // [m][k] bf16
    __shared__ unsigned short Bl[BN][KP];   // [n][k] bf16 (transposed in registers at staging)

    const int tid  = threadIdx.x;
    const int lane = tid & 63;
    const int wave = tid >> 6;
    const int wr   = wave >> 1;       // wave row band (0..1) -> 128 rows
    const int wc   = wave & 1;        // wave col band (0..1) -> 64 cols
    const int nb   = blockIdx.x;      // 0..511
    const int mb   = blockIdx.y;      // 0..3
    const int mbase = mb * BM;
    const int nbase = nb * BN;
    const int l15  = lane & 15;
    const int quad = lane >> 4;

    const float inv_t = 1.0f / temp[0];

    floatx4 acc[8][4] = {};           // 8 row-tiles x 4 col-tiles of 16x16

    const int a_tx = tid & 15;        // float4 col within 64-wide k-chunk
    const int a_ty = tid >> 4;        // row group
    const int b_kx = tid & 7;         // k-octet index
    const int b_ny = tid >> 3;        // n-quad index (0..31)

    for (int kt = 0; kt < 4; ++kt) {
        const int kb = kt * BK;

        // ---- stage A tile: 256 x 64 fp32 -> bf16 LDS [m][k] ----
        #pragma unroll
        for (int r = 0; r < 16; ++r) {
            const int m = r * 16 + a_ty;
            const float4 v = *(const float4*)(A + (size_t)(mbase + m) * DDIM + kb + a_tx * 4);
            unsigned int lo = (unsigned int)f2bf(v.x) | ((unsigned int)f2bf(v.y) << 16);
            unsigned int hi = (unsigned int)f2bf(v.z) | ((unsigned int)f2bf(v.w) << 16);
            *(uint2*)&Al[m][a_tx * 4] = make_uint2(lo, hi);
        }

        // ---- stage B tile: 64 x 128 fp32 -> bf16 LDS [n][k] (register transpose) ----
        {
            float4 vv[8];
            #pragma unroll
            for (int j = 0; j < 8; ++j) {
                const int d = kb + b_kx * 8 + j;
                vv[j] = *(const float4*)(Q + (size_t)d * KQ + nbase + b_ny * 4);
            }
            #pragma unroll
            for (int i = 0; i < 4; ++i) {
                unsigned int w[4];
                #pragma unroll
                for (int p = 0; p < 4; ++p) {
                    const float f0 = ((const float*)&vv[2 * p])[i];
                    const float f1 = ((const float*)&vv[2 * p + 1])[i];
                    w[p] = (unsigned int)f2bf(f0) | ((unsigned int)f2bf(f1) << 16);
                }
                *(uint4*)&Bl[b_ny * 4 + i][b_kx * 8] = make_uint4(w[0], w[1], w[2], w[3]);
            }
        }

        __syncthreads();

        // ---- MFMA: 2 k-steps of 32 ----
        #pragma unroll
        for (int ks = 0; ks < 2; ++ks) {
            const int k0 = ks * 32 + quad * 8;
            short8 af[8], bfr[4];
            #pragma unroll
            for (int i = 0; i < 8; ++i)
                af[i] = *(const short8*)&Al[wr * 128 + i * 16 + l15][k0];
            #pragma unroll
            for (int j = 0; j < 4; ++j)
                bfr[j] = *(const short8*)&Bl[wc * 64 + j * 16 + l15][k0];
            #pragma unroll
            for (int i = 0; i < 8; ++i)
                #pragma unroll
                for (int j = 0; j < 4; ++j)
                    acc[i][j] = __builtin_amdgcn_mfma_f32_16x16x32_bf16(af[i], bfr[j], acc[i][j], 0, 0, 0);
        }

        __syncthreads();
    }

    // ---- epilogue: per-row (over this wave's 64 cols) max + sum(exp) ----
    // C layout: col = lane&15, row = quad*4 + reg  (m89-verified)
    #pragma unroll
    for (int i = 0; i < 8; ++i) {
        #pragma unroll
        for (int r = 0; r < 4; ++r) {
            float mx = fmaxf(fmaxf(acc[i][0][r], acc[i][1][r]),
                             fmaxf(acc[i][2][r], acc[i][3][r]));
            mx *= inv_t;
            mx = fmaxf(mx, __shfl_xor(mx, 1, 64));
            mx = fmaxf(mx, __shfl_xor(mx, 2, 64));
            mx = fmaxf(mx, __shfl_xor(mx, 4, 64));
            mx = fmaxf(mx, __shfl_xor(mx, 8, 64));
            float s = 0.f;
            #pragma unroll
            for (int j = 0; j < 4; ++j)
                s += __expf(acc[i][j][r] * inv_t - mx);
            s += __shfl_xor(s, 1, 64);
            s += __shfl_xor(s, 2, 64);
            s += __shfl_xor(s, 4, 64);
            s += __shfl_xor(s, 8, 64);
            if (l15 == 0) {   // lanes 0,16,32,48: one writer per quad-row
                const int row = mbase + wr * 128 + i * 16 + quad * 4 + r;
                partials[(size_t)row * NPART + nb * 2 + wc] = make_float2(mx, s);
            }
        }
    }
}

__global__ __launch_bounds__(256)
void finalize_rows(const float2* __restrict__ partials,
                   const float* __restrict__ online,
                   const float* __restrict__ mom,
                   const float* __restrict__ temp,
                   float* __restrict__ rowloss)
{
    const int n = blockIdx.x;
    const int t = threadIdx.x;
    __shared__ float redA[4], redB[4], redC[4];

    const float inv_t = 1.0f / temp[0];

    float2 p[4];
    #pragma unroll
    for (int i = 0; i < 4; ++i)
        p[i] = partials[(size_t)n * NPART + t + i * 256];

    // global row max
    float m = fmaxf(fmaxf(p[0].x, p[1].x), fmaxf(p[2].x, p[3].x));
    #pragma unroll
    for (int off = 1; off < 64; off <<= 1) m = fmaxf(m, __shfl_xor(m, off, 64));
    if ((t & 63) == 0) redA[t >> 6] = m;
    __syncthreads();
    const float M = fmaxf(fmaxf(redA[0], redA[1]), fmaxf(redA[2], redA[3]));

    // combined sum of exp
    float s = 0.f;
    #pragma unroll
    for (int i = 0; i < 4; ++i) s += p[i].y * __expf(p[i].x - M);
    #pragma unroll
    for (int off = 1; off < 64; off <<= 1) s += __shfl_xor(s, off, 64);
    if ((t & 63) == 0) redB[t >> 6] = s;

    // positive-pair dot product
    float pv = online[(size_t)n * DDIM + t] * mom[(size_t)n * DDIM + t];
    #pragma unroll
    for (int off = 1; off < 64; off <<= 1) pv += __shfl_xor(pv, off, 64);
    if ((t & 63) == 0) redC[t >> 6] = pv;
    __syncthreads();

    if (t == 0) {
        const float S   = redB[0] + redB[1] + redB[2] + redB[3];
        const float pos = (redC[0] + redC[1] + redC[2] + redC[3]) * inv_t;
        const float M2  = fmaxf(M, pos);
        const float L   = S * __expf(M - M2) + __expf(pos - M2);
        rowloss[n] = M2 + __logf(L) - pos;   // logsumexp over [pos, negs] minus pos logit
    }
}

__global__ __launch_bounds__(256)
void reduce_loss(const float* __restrict__ rowloss, float* __restrict__ out)
{
    const int t = threadIdx.x;
    __shared__ float red[4];
    float s = rowloss[t] + rowloss[t + 256] + rowloss[t + 512] + rowloss[t + 768];
    #pragma unroll
    for (int off = 1; off < 64; off <<= 1) s += __shfl_xor(s, off, 64);
    if ((t & 63) == 0) red[t >> 6] = s;
    __syncthreads();
    if (t == 0)
        out[0] = (red[0] + red[1] + red[2] + red[3]) * (1.0f / (float)NROWS);
        // LOSS_ALPHA*L + (1-LOSS_ALPHA)*L == L in forward
}

extern "C" void kernel_launch(void* const* d_in, const int* in_sizes, int n_in,
                              void* d_out, int out_size, void* d_ws, size_t ws_size,
                              hipStream_t stream)
{
    const float* online = (const float*)d_in[0];   // [1024][256]
    const float* mom    = (const float*)d_in[1];   // [1024][256]
    const float* queue  = (const float*)d_in[2];   // [256][65536]
    const float* temp   = (const float*)d_in[3];   // [1]
    float* out = (float*)d_out;

    // ws layout: partials float2[1024][1024] (8 MB) | rowloss float[1024]
    float2* partials = (float2*)d_ws;
    float*  rowloss  = (float*)((char*)d_ws + (size_t)NROWS * NPART * sizeof(float2));

    gemm_softmax_kernel<<<dim3(KQ / BN, NROWS / BM), 256, 0, stream>>>(online, queue, temp, partials);
    finalize_rows<<<NROWS, 256, 0, stream>>>(partials, online, mom, temp, rowloss);
    reduce_loss<<<1, 256, 0, stream>>>(rowloss, out);
}

// Round 2
// 192.341 us; speedup vs baseline: 1.4897x; 1.4897x over previous
//
#include <hip/hip_runtime.h>
#include <hip/hip_bf16.h>

// loss = mean_n( logsumexp([pos_n, (online@queue)_n]/t) - pos_n/t )   (fwd: alpha mix = identity)
// Pipeline: conv_a (A*1/t -> bf16) ; transpose_q (Q fp32 [256][65536] -> Qt bf16 [65536][256]) ;
//           gemm_softmax (bf16 MFMA + online-softmax partials) ; finalize_rows ; reduce_loss.

#define NROWS 1024
#define DDIM  256
#define KQ    65536

#define BM 128
#define BN 128
#define BK 64
#define NPART 1024      // per row: 512 n-blocks * 2 wave col-bands

typedef short  short8   __attribute__((ext_vector_type(8)));
typedef unsigned short ushort8v __attribute__((ext_vector_type(8)));
typedef float  floatx4  __attribute__((ext_vector_type(4)));

__device__ __forceinline__ unsigned short f2bf(float f) {
    unsigned int u = __float_as_uint(f);
    u += 0x7FFFu + ((u >> 16) & 1u);   // RNE
    return (unsigned short)(u >> 16);
}

__device__ __forceinline__ void gload_lds16(const void* g, void* lds_uniform) {
    __builtin_amdgcn_global_load_lds(
        (const __attribute__((address_space(1))) unsigned int*)g,
        (__attribute__((address_space(3))) unsigned int*)lds_uniform,
        16, 0, 0);
}

// ---- A conversion: bf16(A * 1/t), so GEMM acc are logits directly ----
__global__ __launch_bounds__(256)
void conv_a(const float* __restrict__ A, const float* __restrict__ temp,
            unsigned short* __restrict__ Ab)
{
    const float s = 1.0f / temp[0];
    const int i = blockIdx.x * 256 + threadIdx.x;      // 65536 threads x 4 elems
    const float4 v = ((const float4*)A)[i];
    ushort4 w;
    w.x = f2bf(v.x * s); w.y = f2bf(v.y * s);
    w.z = f2bf(v.z * s); w.w = f2bf(v.w * s);
    *(ushort4*)(Ab + (size_t)i * 4) = w;
}

// ---- Q transpose+convert: Q[256][65536] fp32 -> Qt[65536][256] bf16 ----
__global__ __launch_bounds__(256)
void transpose_q(const float* __restrict__ Q, unsigned short* __restrict__ Qt)
{
    // tile 64 d x 64 n; LDS [n][d] with 16B-chunk XOR swizzle, 128 B rows
    __shared__ __align__(16) unsigned short T[64 * 64];
    const int t  = threadIdx.x;
    const int nb = blockIdx.x;      // 1024
    const int db = blockIdx.y;      // 4
    const int cn = t & 3;           // n float4-chunk
    const int d  = t >> 2;          // 0..63

    #pragma unroll
    for (int pass = 0; pass < 4; ++pass) {
        const int nl0 = pass * 16 + cn * 4;
        const float4 v = *(const float4*)(Q + (size_t)(db * 64 + d) * KQ + nb * 64 + nl0);
        const float fv[4] = {v.x, v.y, v.z, v.w};
        #pragma unroll
        for (int j = 0; j < 4; ++j) {
            const int n = nl0 + j;
            const int chunk = (d >> 3) ^ (n & 7);
            T[n * 64 + chunk * 8 + (d & 7)] = f2bf(fv[j]);
        }
    }
    __syncthreads();
    #pragma unroll
    for (int pass = 0; pass < 2; ++pass) {
        const int n = pass * 32 + (t >> 3);
        const int x = t & 7;                   // logical d-chunk
        const int pc = x ^ (n & 7);            // physical chunk
        const ushort8v w = *(const ushort8v*)&T[n * 64 + pc * 8];
        *(ushort8v*)(Qt + (size_t)(nb * 64 + n) * DDIM + db * 64 + x * 8) = w;
    }
}

// ---- main GEMM + online-softmax partials ----
__global__ __launch_bounds__(256, 3)
void gemm_softmax(const unsigned short* __restrict__ Ab,   // [1024][256] bf16 (pre-scaled 1/t)
                  const unsigned short* __restrict__ Qt,   // [65536][256] bf16
                  float2* __restrict__ partials)           // [1024][NPART]
{
    __shared__ __align__(16) unsigned short Al[BM * BK];   // 16 KB, swizzled, 128 B rows
    __shared__ __align__(16) unsigned short Bl[BN * BK];   // 16 KB

    const int tid  = threadIdx.x;
    const int lane = tid & 63;
    const int wave = tid >> 6;
    const int wr   = wave >> 1;      // row band (64 rows)
    const int wc   = wave & 1;       // col band (64 cols)
    const int nb   = blockIdx.x;     // 0..511
    const int mb   = blockIdx.y;     // 0..7
    const int mbase = mb * BM;
    const int nbase = nb * BN;
    const int l15  = lane & 15;
    const int quad = lane >> 4;

    // staging map: call c, lane l -> LDS byte o = (wave*4+c)*1024 + l*16
    // prow = o>>7 ; physical chunk x = (o>>4)&7 ; logical chunk = x ^ (prow&7)
    int goff[4], lbase[4];
    #pragma unroll
    for (int c = 0; c < 4; ++c) {
        const int o = (wave * 4 + c) * 1024 + lane * 16;
        const int prow = o >> 7;
        const int chunk = ((o >> 4) & 7) ^ (prow & 7);
        goff[c]  = prow * DDIM + chunk * 8;      // element offset (kb added per kt)
        lbase[c] = (wave * 4 + c) * 1024;        // wave-uniform LDS byte base
    }

    floatx4 acc[4][4] = {};
    const int xorp = l15 & 7;

    for (int kt = 0; kt < 4; ++kt) {
        const int kb = kt * BK;
        #pragma unroll
        for (int c = 0; c < 4; ++c) {
            gload_lds16(Ab + (size_t)mbase * DDIM + kb + goff[c], (char*)Al + lbase[c]);
            gload_lds16(Qt + (size_t)nbase * DDIM + kb + goff[c], (char*)Bl + lbase[c]);
        }
        __syncthreads();

        #pragma unroll
        for (int ks = 0; ks < 2; ++ks) {
            const int cx = (((ks * 4 + quad) ^ xorp) * 16);
            short8 af[4], bfv[4];
            #pragma unroll
            for (int i = 0; i < 4; ++i)
                af[i] = *(const short8*)((const char*)Al + (wr * 64 + i * 16 + l15) * 128 + cx);
            #pragma unroll
            for (int j = 0; j < 4; ++j)
                bfv[j] = *(const short8*)((const char*)Bl + (wc * 64 + j * 16 + l15) * 128 + cx);
            #pragma unroll
            for (int i = 0; i < 4; ++i)
                #pragma unroll
                for (int j = 0; j < 4; ++j)
                    acc[i][j] = __builtin_amdgcn_mfma_f32_16x16x32_bf16(af[i], bfv[j], acc[i][j], 0, 0, 0);
        }
        __syncthreads();
    }

    // epilogue: acc are logits (A pre-scaled). C layout: col=lane&15, row=quad*4+reg.
    #pragma unroll
    for (int i = 0; i < 4; ++i) {
        #pragma unroll
        for (int r = 0; r < 4; ++r) {
            float mx = fmaxf(fmaxf(acc[i][0][r], acc[i][1][r]),
                             fmaxf(acc[i][2][r], acc[i][3][r]));
            mx = fmaxf(mx, __shfl_xor(mx, 1, 64));
            mx = fmaxf(mx, __shfl_xor(mx, 2, 64));
            mx = fmaxf(mx, __shfl_xor(mx, 4, 64));
            mx = fmaxf(mx, __shfl_xor(mx, 8, 64));
            float s = 0.f;
            #pragma unroll
            for (int j = 0; j < 4; ++j)
                s += __expf(acc[i][j][r] - mx);
            s += __shfl_xor(s, 1, 64);
            s += __shfl_xor(s, 2, 64);
            s += __shfl_xor(s, 4, 64);
            s += __shfl_xor(s, 8, 64);
            if (l15 == 0) {
                const int row = mbase + wr * 64 + i * 16 + quad * 4 + r;
                partials[(size_t)row * NPART + nb * 2 + wc] = make_float2(mx, s);
            }
        }
    }
}

__global__ __launch_bounds__(256)
void finalize_rows(const float2* __restrict__ partials,
                   const float* __restrict__ online,
                   const float* __restrict__ mom,
                   const float* __restrict__ temp,
                   float* __restrict__ rowloss)
{
    const int n = blockIdx.x;
    const int t = threadIdx.x;
    __shared__ float redA[4], redB[4], redC[4];

    const float inv_t = 1.0f / temp[0];

    float2 p[4];
    #pragma unroll
    for (int i = 0; i < 4; ++i)
        p[i] = partials[(size_t)n * NPART + t + i * 256];

    float m = fmaxf(fmaxf(p[0].x, p[1].x), fmaxf(p[2].x, p[3].x));
    #pragma unroll
    for (int off = 1; off < 64; off <<= 1) m = fmaxf(m, __shfl_xor(m, off, 64));
    if ((t & 63) == 0) redA[t >> 6] = m;
    __syncthreads();
    const float M = fmaxf(fmaxf(redA[0], redA[1]), fmaxf(redA[2], redA[3]));

    float s = 0.f;
    #pragma unroll
    for (int i = 0; i < 4; ++i) s += p[i].y * __expf(p[i].x - M);
    #pragma unroll
    for (int off = 1; off < 64; off <<= 1) s += __shfl_xor(s, off, 64);
    if ((t & 63) == 0) redB[t >> 6] = s;

    float pv = online[(size_t)n * DDIM + t] * mom[(size_t)n * DDIM + t];
    #pragma unroll
    for (int off = 1; off < 64; off <<= 1) pv += __shfl_xor(pv, off, 64);
    if ((t & 63) == 0) redC[t >> 6] = pv;
    __syncthreads();

    if (t == 0) {
        const float S   = redB[0] + redB[1] + redB[2] + redB[3];
        const float pos = (redC[0] + redC[1] + redC[2] + redC[3]) * inv_t;
        const float M2  = fmaxf(M, pos);
        const float L   = S * __expf(M - M2) + __expf(pos - M2);
        rowloss[n] = M2 + __logf(L) - pos;
    }
}

__global__ __launch_bounds__(256)
void reduce_loss(const float* __restrict__ rowloss, float* __restrict__ out)
{
    const int t = threadIdx.x;
    __shared__ float red[4];
    float s = rowloss[t] + rowloss[t + 256] + rowloss[t + 512] + rowloss[t + 768];
    #pragma unroll
    for (int off = 1; off < 64; off <<= 1) s += __shfl_xor(s, off, 64);
    if ((t & 63) == 0) red[t >> 6] = s;
    __syncthreads();
    if (t == 0)
        out[0] = (red[0] + red[1] + red[2] + red[3]) * (1.0f / (float)NROWS);
}

extern "C" void kernel_launch(void* const* d_in, const int* in_sizes, int n_in,
                              void* d_out, int out_size, void* d_ws, size_t ws_size,
                              hipStream_t stream)
{
    const float* online = (const float*)d_in[0];   // [1024][256]
    const float* mom    = (const float*)d_in[1];   // [1024][256]
    const float* queue  = (const float*)d_in[2];   // [256][65536]
    const float* temp   = (const float*)d_in[3];   // [1]
    float* out = (float*)d_out;

    // ws layout: Qt bf16 [65536][256] (32 MB) | Ab bf16 [1024][256] (512 KB)
    //            | partials float2[1024][1024] (8 MB) | rowloss (4 KB)
    char* ws = (char*)d_ws;
    unsigned short* Qt = (unsigned short*)ws;                                  // 33554432 B
    unsigned short* Ab = (unsigned short*)(ws + (size_t)33554432);             // 524288 B
    float2* partials   = (float2*)(ws + (size_t)33554432 + 524288);            // 8388608 B
    float*  rowloss    = (float*)(ws + (size_t)33554432 + 524288 + 8388608);

    conv_a<<<NROWS * DDIM / 1024, 256, 0, stream>>>(online, temp, Ab);
    transpose_q<<<dim3(KQ / 64, DDIM / 64), 256, 0, stream>>>(queue, Qt);
    gemm_softmax<<<dim3(KQ / BN, NROWS / BM), 256, 0, stream>>>(Ab, Qt, partials);
    finalize_rows<<<NROWS, 256, 0, stream>>>(partials, online, mom, temp, rowloss);
    reduce_loss<<<1, 256, 0, stream>>>(rowloss, out);
}